// Round 21
// baseline (80.222 us; speedup 1.0000x reference)
//
#include <hip/hip_runtime.h>
#include <math.h>

#define NN 8192
#define DD 512
#define MM 4
#define EE 131072
#define NB2 4   // 16-pair batches per wave; 1024 blocks x 4 waves x 4 x 16 = 262144

typedef float  floatx2 __attribute__((ext_vector_type(2)));
typedef _Float16 h2    __attribute__((ext_vector_type(2)));
typedef _Float16 f16x8 __attribute__((ext_vector_type(8)));
typedef float  f32x4   __attribute__((ext_vector_type(4)));

#define K214 0x74007400u   // h2(16384.0, 16384.0) = 2^14 per lane

union F8U { f16x8 v; h2 h[4]; unsigned u[4]; };

__device__ inline h2 pkrtz(float a, float b) {
    return __builtin_bit_cast(h2, __builtin_amdgcn_cvt_pkrtz(a, b));
}

__device__ inline float fdot2a(h2 a, h2 b, float c) {
#if __has_builtin(__builtin_amdgcn_fdot2)
    return __builtin_amdgcn_fdot2(a, b, c, false);
#else
    return c + (float)a[0] * (float)b[0] + (float)a[1] * (float)b[1];
#endif
}

// fp4 e2m1 dequant bit-trick: nibble (s e1 e0 m) -> f16 bits (s<<15)|(eem<<9)
// gives value * 2^-14 EXACTLY (0.5 -> f16 denormal 2^-15).
// u32 of 8 nibbles -> 4 h2 raw pairs; pairing (k, k+4).
__device__ inline void deq4raw(unsigned v, h2 r[4]) {
    #pragma unroll
    for (int k = 0; k < 4; ++k) {
        unsigned t = v >> (4 * k);
        unsigned x = ((t & 0x00070007u) << 9) | ((t & 0x00080008u) << 12);
        r[k] = __builtin_bit_cast(h2, x);
    }
}

template <int CTRL>
__device__ inline float dpp_add(float v) {
    int x = __builtin_amdgcn_update_dpp(0, __builtin_bit_cast(int, v), CTRL, 0xf, 0xf, true);
    return v + __builtin_bit_cast(float, x);
}

// ---------------------------------------------------------------------------
// Kernel 1 (r19/r20-verified, unchanged): fp4 e2m1 table (nibble/dim,
// 256B/row), midpoint-ladder quantizer; reciprocal norms from the SAME
// dequantized f16 values and pk_mul chain as the pair kernel. rn_t[m][n]
// carries the 2^7 scale that cancels acc's 2^-14. Zeroes out[0].
// ---------------------------------------------------------------------------
__global__ __launch_bounds__(256) void quant_norm_kernel(const float* __restrict__ emb,
                                                         const float* __restrict__ mh,
                                                         unsigned* __restrict__ q4,
                                                         float* __restrict__ rn_t,
                                                         float* __restrict__ out) {
    if (blockIdx.x == 0 && threadIdx.x == 0) out[0] = 0.0f;

    const int lane = threadIdx.x & 63;
    const unsigned n = blockIdx.x * 4 + (threadIdx.x >> 6);

    const float* er = emb + n * DD + lane * 8;
    float4 e0 = *(const float4*)(er);
    float4 e1 = *(const float4*)(er + 4);
    float xv[8] = {e0.x, e0.y, e0.z, e0.w, e1.x, e1.y, e1.z, e1.w};

    unsigned pack = 0;
    #pragma unroll
    for (int k = 0; k < 8; ++k) {
        float a = fabsf(xv[k]);
        unsigned mag = (unsigned)(a >= 0.25f) + (a >= 0.75f) + (a >= 1.25f) +
                       (a >= 1.75f) + (a >= 2.5f) + (a >= 3.5f) + (a >= 5.0f);
        unsigned nib = mag | ((__builtin_bit_cast(unsigned, xv[k]) >> 28) & 8u);
        pack |= nib << (4 * k);
    }
    q4[(n << 6) | lane] = pack;

    h2 raw[4];
    deq4raw(pack, raw);
    const h2 K = __builtin_bit_cast(h2, K214);
    h2 prs[4];
    #pragma unroll
    for (int k = 0; k < 4; ++k) {
        h2 full = raw[k] * K;
        prs[k] = full * raw[k];
    }

    const float* mb = mh + lane * 8;
    float ss[4];
    #pragma unroll
    for (int m = 0; m < 4; ++m) {
        float4 m0 = *(const float4*)(mb + m * DD);
        float4 m1 = *(const float4*)(mb + m * DD + 4);
        h2 w0 = pkrtz(m0.x * m0.x, m1.x * m1.x);
        h2 w1 = pkrtz(m0.y * m0.y, m1.y * m1.y);
        h2 w2 = pkrtz(m0.z * m0.z, m1.z * m1.z);
        h2 w3 = pkrtz(m0.w * m0.w, m1.w * m1.w);
        float s = 0.f;
        s = fdot2a(prs[0], w0, s);
        s = fdot2a(prs[1], w1, s);
        s = fdot2a(prs[2], w2, s);
        s = fdot2a(prs[3], w3, s);
        ss[m] = s;
    }

    ss[0] = dpp_add<0x111>(ss[0]); ss[1] = dpp_add<0x111>(ss[1]);
    ss[2] = dpp_add<0x111>(ss[2]); ss[3] = dpp_add<0x111>(ss[3]);
    ss[0] = dpp_add<0x112>(ss[0]); ss[1] = dpp_add<0x112>(ss[1]);
    ss[2] = dpp_add<0x112>(ss[2]); ss[3] = dpp_add<0x112>(ss[3]);
    ss[0] = dpp_add<0x114>(ss[0]); ss[1] = dpp_add<0x114>(ss[1]);
    ss[2] = dpp_add<0x114>(ss[2]); ss[3] = dpp_add<0x114>(ss[3]);
    ss[0] = dpp_add<0x118>(ss[0]); ss[1] = dpp_add<0x118>(ss[1]);
    ss[2] = dpp_add<0x118>(ss[2]); ss[3] = dpp_add<0x118>(ss[3]);
    ss[0] = dpp_add<0x142>(ss[0]); ss[1] = dpp_add<0x142>(ss[1]);
    ss[2] = dpp_add<0x142>(ss[2]); ss[3] = dpp_add<0x142>(ss[3]);
    ss[0] = dpp_add<0x143>(ss[0]); ss[1] = dpp_add<0x143>(ss[1]);
    ss[2] = dpp_add<0x143>(ss[2]); ss[3] = dpp_add<0x143>(ss[3]);

    if (lane == 63) {
        rn_t[0 * NN + n] = 1.0f / fmaxf(sqrtf(ss[0]), 1e-12f);
        rn_t[1 * NN + n] = 1.0f / fmaxf(sqrtf(ss[1]), 1e-12f);
        rn_t[2 * NN + n] = 1.0f / fmaxf(sqrtf(ss[2]), 1e-12f);
        rn_t[3 * NN + n] = 1.0f / fmaxf(sqrtf(ss[3]), 1e-12f);
    }
}

// ---------------------------------------------------------------------------
// Kernel 2: wave-independent MFMA, ZERO barriers/DMA/row-LDS. Each wave owns
// 16 pairs per batch, full K=512 (16 MFMAs, two 8-deep acc chains). A-frag
// gathered DIRECTLY into registers: lane (p,kq) reads u32 at
// row[p]*256 + mf*16 + kq*4 (16 mf walk each 256B row through L1).
// B-weights from the 4KB r19-verified wlds (broadcast reads). Epilogue =
// r14-verified wave-local mapping. sched_barrier(0) pins gather issue.
// ---------------------------------------------------------------------------
__global__ __launch_bounds__(256) void pair_kernel(const int* __restrict__ edges,
                                                   const int* __restrict__ nedges,
                                                   const unsigned char* __restrict__ qtab,
                                                   const float* __restrict__ mh,
                                                   const float* __restrict__ rn_t,
                                                   float* __restrict__ out) {
    __shared__ _Float16 wlds[2048];    // 4 KiB B-weights
    __shared__ float wsum[4];

    const int t = threadIdx.x;
    {   // stage squared f16 weights; slot kk*16+kq*4+m; (k,k+4) pairing (r19)
        int m_ = t >> 6, sl = t & 63;
        const float* mb = mh + m_ * DD + sl * 8;
        float4 m0 = *(const float4*)(mb);
        float4 m1 = *(const float4*)(mb + 4);
        F8U wv;
        wv.h[0] = pkrtz(m0.x * m0.x, m1.x * m1.x);
        wv.h[1] = pkrtz(m0.y * m0.y, m1.y * m1.y);
        wv.h[2] = pkrtz(m0.z * m0.z, m1.z * m1.z);
        wv.h[3] = pkrtz(m0.w * m0.w, m1.w * m1.w);
        int s = (sl >> 2) * 16 + (sl & 3) * 4 + m_;
        *(f16x8*)(&wlds[s * 8]) = wv.v;
    }
    __syncthreads();

    const int lane = t & 63;
    const int w    = t >> 6;
    const int p    = lane & 15;   // pair within batch / D-col
    const int kq   = lane >> 4;   // k-quad
    const int m    = p & 3;

    const _Float16* wbase = &wlds[(kq * 4 + m) * 8];
    const float*    rm    = rn_t + m * NN;
    const h2 K = __builtin_bit_cast(h2, K214);

    const int  gw   = blockIdx.x * 4 + w;        // 4096 waves x 64 pairs
    const int  base = gw * (NB2 * 16);
    const bool pos  = base < EE;
    const int* eb   = pos ? edges : nedges;
    const int  lb   = pos ? base : base - EE;

    float lsum = 0.f;

    #pragma unroll 1
    for (int bt = 0; bt < NB2; ++bt) {
        const int lb2 = lb + bt * 16;

        // per-lane row indices (lane p -> pair p; 4x replicated, coalesced)
        int vi = eb[lb2 + p];
        int vj = eb[lb2 + EE + p];
        const unsigned char* ra = qtab + (size_t)((unsigned)vi * 256u + kq * 4);
        const unsigned char* rb = qtab + (size_t)((unsigned)vj * 256u + kq * 4);

        // issue ALL 32 fragment gathers up-front (independent; L1-walked)
        unsigned ua[16], ub[16];
        #pragma unroll
        for (int mf = 0; mf < 16; ++mf) {
            ua[mf] = *(const unsigned*)(ra + mf * 16);
            ub[mf] = *(const unsigned*)(rb + mf * 16);
        }

        // epilogue operands (independent chain)
        int4 pi4 = *(const int4*)(eb + lb2 + kq * 4);
        int4 pj4 = *(const int4*)(eb + lb2 + EE + kq * 4);
        float rw0 = rm[pi4.x] * rm[pj4.x];
        float rw1 = rm[pi4.y] * rm[pj4.y];
        float rw2 = rm[pi4.z] * rm[pj4.z];
        float rw3 = rm[pi4.w] * rm[pj4.w];

        __builtin_amdgcn_sched_barrier(0);   // gathers stay issued above

        f32x4 acc0 = {0.f, 0.f, 0.f, 0.f};
        f32x4 acc1 = {0.f, 0.f, 0.f, 0.f};
        #pragma unroll
        for (int mf = 0; mf < 16; mf += 2) {
            {
                h2 xa[4], xb[4];
                deq4raw(ua[mf], xa);
                deq4raw(ub[mf], xb);
                F8U pr;
                #pragma unroll
                for (int k = 0; k < 4; ++k) pr.h[k] = (xa[k] * K) * xb[k];
                acc0 = __builtin_amdgcn_mfma_f32_16x16x32_f16(
                           pr.v, *(const f16x8*)(wbase + mf * 128), acc0, 0, 0, 0);
            }
            {
                h2 xa[4], xb[4];
                deq4raw(ua[mf + 1], xa);
                deq4raw(ub[mf + 1], xb);
                F8U pr;
                #pragma unroll
                for (int k = 0; k < 4; ++k) pr.h[k] = (xa[k] * K) * xb[k];
                acc1 = __builtin_amdgcn_mfma_f32_16x16x32_f16(
                           pr.v, *(const f16x8*)(wbase + (mf + 1) * 128), acc1, 0, 0, 0);
            }
        }

        // ---- r14-verified epilogue (wave-local; acc 2^-14 x rw 2^14 cancels)
        float v0 = (acc0[0] + acc1[0]) * rw0;
        float v1 = (acc0[1] + acc1[1]) * rw1;
        float v2 = (acc0[2] + acc1[2]) * rw2;
        float v3 = (acc0[3] + acc1[3]) * rw3;
        v0 = dpp_add<0x111>(v0); v1 = dpp_add<0x111>(v1);
        v2 = dpp_add<0x111>(v2); v3 = dpp_add<0x111>(v3);
        v0 = dpp_add<0x112>(v0); v1 = dpp_add<0x112>(v1);
        v2 = dpp_add<0x112>(v2); v3 = dpp_add<0x112>(v3);
        // lane p==3 (per kq row) holds full m-sums for pairs kq*4 + 0..3

        float d0 = 1.000001f - 0.25f * v0;
        float d1 = 1.000001f - 0.25f * v1;
        float d2 = 1.000001f - 0.25f * v2;
        float d3 = 1.000001f - 0.25f * v3;
        float a0 = pos ? d0 : fmaf(-0.5f, d0, 1.0f);
        float a1 = pos ? d1 : fmaf(-0.5f, d1, 1.0f);
        float a2 = pos ? d2 : fmaf(-0.5f, d2, 1.0f);
        float a3 = pos ? d3 : fmaf(-0.5f, d3, 1.0f);
        float lg = __logf(fmaxf(a0, 1e-8f)) + __logf(fmaxf(a1, 1e-8f)) +
                   __logf(fmaxf(a2, 1e-8f)) + __logf(fmaxf(a3, 1e-8f));
        lsum += (p == 3) ? lg : 0.f;
    }

    // wave reduce (nonzero lanes 3,19,35,51) then block combine, 1 atomic
    lsum = dpp_add<0x111>(lsum);
    lsum = dpp_add<0x112>(lsum);
    lsum = dpp_add<0x114>(lsum);
    lsum = dpp_add<0x118>(lsum);
    lsum = dpp_add<0x142>(lsum);
    lsum = dpp_add<0x143>(lsum);
    if (lane == 63) wsum[w] = lsum;
    __syncthreads();
    if (t == 0) {
        float s = wsum[0] + wsum[1] + wsum[2] + wsum[3];
        atomicAdd(out, -s);
    }
}

extern "C" void kernel_launch(void* const* d_in, const int* in_sizes, int n_in,
                              void* d_out, int out_size, void* d_ws, size_t ws_size,
                              hipStream_t stream) {
    const int*   edges  = (const int*)d_in[0];
    const int*   nedges = (const int*)d_in[1];
    const float* emb    = (const float*)d_in[2];
    const float* mh     = (const float*)d_in[3];
    float* out = (float*)d_out;

    unsigned* q4   = (unsigned*)d_ws;                             // 2 MiB fp4 table
    float*    rn_t = (float*)((char*)d_ws + (size_t)NN * DD / 2); // 128 KiB, [m][n]

    quant_norm_kernel<<<NN / 4, 256, 0, stream>>>(emb, mh, q4, rn_t, out);
    pair_kernel<<<(2 * EE) / (4 * NB2 * 16), 256, 0, stream>>>(edges, nedges,
                                                               (const unsigned char*)q4,
                                                               mh, rn_t, out);
}

// Round 22
// 44.843 us; speedup vs baseline: 1.7889x; 1.7889x over previous
//
#include <hip/hip_runtime.h>
#include <math.h>

#define NN 8192
#define DD 512
#define MM 4
#define EE 131072
#define NBW 4   // 16-pair batches per wave; 1024 blocks x 4 waves x 4 x 16

typedef float  floatx2 __attribute__((ext_vector_type(2)));
typedef _Float16 h2    __attribute__((ext_vector_type(2)));
typedef _Float16 f16x8 __attribute__((ext_vector_type(8)));
typedef float  f32x4   __attribute__((ext_vector_type(4)));

#define K214 0x74007400u   // h2(16384.0, 16384.0) = 2^14 per lane

union F8U { f16x8 v; h2 h[4]; unsigned u[4]; };

__device__ inline h2 pkrtz(float a, float b) {
    return __builtin_bit_cast(h2, __builtin_amdgcn_cvt_pkrtz(a, b));
}

__device__ inline float fdot2a(h2 a, h2 b, float c) {
#if __has_builtin(__builtin_amdgcn_fdot2)
    return __builtin_amdgcn_fdot2(a, b, c, false);
#else
    return c + (float)a[0] * (float)b[0] + (float)a[1] * (float)b[1];
#endif
}

// fp4 e2m1 dequant bit-trick: nibble -> f16 bits (s<<15)|(eem<<9) = value*2^-14
__device__ inline void deq4raw(unsigned v, h2 r[4]) {
    #pragma unroll
    for (int k = 0; k < 4; ++k) {
        unsigned t = v >> (4 * k);
        unsigned x = ((t & 0x00070007u) << 9) | ((t & 0x00080008u) << 12);
        r[k] = __builtin_bit_cast(h2, x);
    }
}

template <int CTRL>
__device__ inline float dpp_add(float v) {
    int x = __builtin_amdgcn_update_dpp(0, __builtin_bit_cast(int, v), CTRL, 0xf, 0xf, true);
    return v + __builtin_bit_cast(float, x);
}

__device__ inline void dma16(const void* g, void* l) {
    __builtin_amdgcn_global_load_lds(
        (const __attribute__((address_space(1))) void*)g,
        (__attribute__((address_space(3))) void*)l, 16, 0, 0);
}

// ---------------------------------------------------------------------------
// Kernel 1 (r19/r20/r21-verified, unchanged): fp4 e2m1 table + recip norms
// from the SAME dequantized values; rn_t[m][n] carries the 2^7 scale.
// ---------------------------------------------------------------------------
__global__ __launch_bounds__(256) void quant_norm_kernel(const float* __restrict__ emb,
                                                         const float* __restrict__ mh,
                                                         unsigned* __restrict__ q4,
                                                         float* __restrict__ rn_t,
                                                         float* __restrict__ out) {
    if (blockIdx.x == 0 && threadIdx.x == 0) out[0] = 0.0f;

    const int lane = threadIdx.x & 63;
    const unsigned n = blockIdx.x * 4 + (threadIdx.x >> 6);

    const float* er = emb + n * DD + lane * 8;
    float4 e0 = *(const float4*)(er);
    float4 e1 = *(const float4*)(er + 4);
    float xv[8] = {e0.x, e0.y, e0.z, e0.w, e1.x, e1.y, e1.z, e1.w};

    unsigned pack = 0;
    #pragma unroll
    for (int k = 0; k < 8; ++k) {
        float a = fabsf(xv[k]);
        unsigned mag = (unsigned)(a >= 0.25f) + (a >= 0.75f) + (a >= 1.25f) +
                       (a >= 1.75f) + (a >= 2.5f) + (a >= 3.5f) + (a >= 5.0f);
        unsigned nib = mag | ((__builtin_bit_cast(unsigned, xv[k]) >> 28) & 8u);
        pack |= nib << (4 * k);
    }
    q4[(n << 6) | lane] = pack;

    h2 raw[4];
    deq4raw(pack, raw);
    const h2 K = __builtin_bit_cast(h2, K214);
    h2 prs[4];
    #pragma unroll
    for (int k = 0; k < 4; ++k) {
        h2 full = raw[k] * K;
        prs[k] = full * raw[k];
    }

    const float* mb = mh + lane * 8;
    float ss[4];
    #pragma unroll
    for (int m = 0; m < 4; ++m) {
        float4 m0 = *(const float4*)(mb + m * DD);
        float4 m1 = *(const float4*)(mb + m * DD + 4);
        h2 w0 = pkrtz(m0.x * m0.x, m1.x * m1.x);
        h2 w1 = pkrtz(m0.y * m0.y, m1.y * m1.y);
        h2 w2 = pkrtz(m0.z * m0.z, m1.z * m1.z);
        h2 w3 = pkrtz(m0.w * m0.w, m1.w * m1.w);
        float s = 0.f;
        s = fdot2a(prs[0], w0, s);
        s = fdot2a(prs[1], w1, s);
        s = fdot2a(prs[2], w2, s);
        s = fdot2a(prs[3], w3, s);
        ss[m] = s;
    }

    ss[0] = dpp_add<0x111>(ss[0]); ss[1] = dpp_add<0x111>(ss[1]);
    ss[2] = dpp_add<0x111>(ss[2]); ss[3] = dpp_add<0x111>(ss[3]);
    ss[0] = dpp_add<0x112>(ss[0]); ss[1] = dpp_add<0x112>(ss[1]);
    ss[2] = dpp_add<0x112>(ss[2]); ss[3] = dpp_add<0x112>(ss[3]);
    ss[0] = dpp_add<0x114>(ss[0]); ss[1] = dpp_add<0x114>(ss[1]);
    ss[2] = dpp_add<0x114>(ss[2]); ss[3] = dpp_add<0x114>(ss[3]);
    ss[0] = dpp_add<0x118>(ss[0]); ss[1] = dpp_add<0x118>(ss[1]);
    ss[2] = dpp_add<0x118>(ss[2]); ss[3] = dpp_add<0x118>(ss[3]);
    ss[0] = dpp_add<0x142>(ss[0]); ss[1] = dpp_add<0x142>(ss[1]);
    ss[2] = dpp_add<0x142>(ss[2]); ss[3] = dpp_add<0x142>(ss[3]);
    ss[0] = dpp_add<0x143>(ss[0]); ss[1] = dpp_add<0x143>(ss[1]);
    ss[2] = dpp_add<0x143>(ss[2]); ss[3] = dpp_add<0x143>(ss[3]);

    if (lane == 63) {
        rn_t[0 * NN + n] = 1.0f / fmaxf(sqrtf(ss[0]), 1e-12f);
        rn_t[1 * NN + n] = 1.0f / fmaxf(sqrtf(ss[1]), 1e-12f);
        rn_t[2 * NN + n] = 1.0f / fmaxf(sqrtf(ss[2]), 1e-12f);
        rn_t[3 * NN + n] = 1.0f / fmaxf(sqrtf(ss[3]), 1e-12f);
    }
}

// ---------------------------------------------------------------------------
// Kernel 2: WAVE-INDEPENDENT DMA pipeline — zero inter-wave barriers.
// Per wave: private 2x4KB phase buffers; batch = 16 pairs = 2 K-phases.
// One DMA = 4 pairs' half-rows (8x128B contiguous). vmcnt is per-wave, so
// counted waits replace barriers entirely (r9 correctness precedent).
// Chunk-XOR ^pair source pre-swizzle; fragment ds_read_b32 2-way (free).
// Dequant/MFMA/epilogue byte-identical to r19/r21 (verified).
// ---------------------------------------------------------------------------
__global__ __launch_bounds__(256) void pair_kernel(const int* __restrict__ edges,
                                                   const int* __restrict__ nedges,
                                                   const unsigned char* __restrict__ qtab,
                                                   const float* __restrict__ mh,
                                                   const float* __restrict__ rn_t,
                                                   float* __restrict__ out) {
    __shared__ __align__(16) unsigned char stage[4][8192];   // 32 KiB (8K/wave)
    __shared__ _Float16 wlds[2048];                          // 4 KiB weights
    __shared__ float wsum[4];

    const int t = threadIdx.x;
    {   // stage squared f16 weights; slot kk*16+kq*4+m; (k,k+4) pairing (r19)
        int m_ = t >> 6, sl = t & 63;
        const float* mb = mh + m_ * DD + sl * 8;
        float4 m0 = *(const float4*)(mb);
        float4 m1 = *(const float4*)(mb + 4);
        F8U wv;
        wv.h[0] = pkrtz(m0.x * m0.x, m1.x * m1.x);
        wv.h[1] = pkrtz(m0.y * m0.y, m1.y * m1.y);
        wv.h[2] = pkrtz(m0.z * m0.z, m1.z * m1.z);
        wv.h[3] = pkrtz(m0.w * m0.w, m1.w * m1.w);
        int s = (sl >> 2) * 16 + (sl & 3) * 4 + m_;
        *(f16x8*)(&wlds[s * 8]) = wv.v;
    }
    __syncthreads();

    const int lane = t & 63;
    const int w    = t >> 6;
    const int p    = lane & 15;   // pair / D-col
    const int kq   = lane >> 4;   // k-quad
    const int m    = p & 3;
    // DMA lane decomposition
    const int q    = lane >> 4;         // pair-within-DMA-group
    const int side = (lane >> 3) & 1;   // 0 = row i, 1 = row j
    const int c    = lane & 7;          // 16B chunk within half-row
    const int sEE  = side * EE;

    unsigned char* bufA = &stage[w][0];
    unsigned char* bufB = &stage[w][4096];

    const _Float16* wbase = &wlds[(kq * 4 + m) * 8];
    const float*    rm    = rn_t + m * NN;
    const h2 K = __builtin_bit_cast(h2, K214);

    const int  gw   = blockIdx.x * 4 + w;     // 4096 waves x 64 pairs
    const int  base = gw * (NBW * 16);
    const bool pos  = base < EE;
    const int* eb   = pos ? edges : nedges;
    const int  lb   = pos ? base : base - EE;

    // per-lane DMA row indices for current batch (side-specific)
    int rows[4];
    #pragma unroll
    for (int du = 0; du < 4; ++du) rows[du] = eb[lb + sEE + du * 4 + q];

    // prologue: phase-0 of batch 0 into bufA
    #pragma unroll
    for (int du = 0; du < 4; ++du) {
        int pr = du * 4 + q;
        const unsigned char* src = qtab + ((size_t)(unsigned)rows[du] << 8)
                                 + (unsigned)(((c ^ (pr & 7)) << 4));
        dma16(src, bufA + du * 1024);
    }

    float lsum = 0.f;

    #pragma unroll 1
    for (int bt = 0; bt < NBW; ++bt) {
        const int  lb2  = lb + bt * 16;
        const bool more = (bt + 1 < NBW);

        // --- issue rw loads + next-batch index gathers (drain coincides
        //     with the phase-0 wait; r15/r17 lesson honored: dependent
        //     chains issued before NEW DMAs) ---
        int4 pi4 = *(const int4*)(eb + lb2 + kq * 4);
        int4 pj4 = *(const int4*)(eb + lb2 + EE + kq * 4);
        float rw0 = rm[pi4.x] * rm[pj4.x];
        float rw1 = rm[pi4.y] * rm[pj4.y];
        float rw2 = rm[pi4.z] * rm[pj4.z];
        float rw3 = rm[pi4.w] * rm[pj4.w];
        int rowsN[4];
        #pragma unroll
        for (int du = 0; du < 4; ++du)
            rowsN[du] = more ? eb[lb2 + 16 + sEE + du * 4 + q] : 0;

        // --- stage phase 1 of THIS batch into bufB (uses rows[], whose
        //     consumption above already forced the phase-0 drain) ---
        asm volatile("s_waitcnt lgkmcnt(0)" ::: "memory");
        __builtin_amdgcn_sched_barrier(0);
        #pragma unroll
        for (int du = 0; du < 4; ++du) {
            int pr = du * 4 + q;
            const unsigned char* src = qtab + ((size_t)(unsigned)rows[du] << 8)
                                     + 128u + (unsigned)(((c ^ (pr & 7)) << 4));
            dma16(src, bufB + du * 1024);
        }
        asm volatile("s_waitcnt vmcnt(4)" ::: "memory");   // phase-0 data ready

        // --- compute phase 0 from bufA (ph1 DMAs in flight) ---
        f32x4 acc0 = {0.f, 0.f, 0.f, 0.f};
        f32x4 acc1 = {0.f, 0.f, 0.f, 0.f};
        #pragma unroll
        for (int mf8 = 0; mf8 < 8; mf8 += 2) {
            {
                unsigned ioff = (unsigned)(p * 256 + ((mf8 ^ (p & 7)) << 4) + kq * 4);
                unsigned ua = *(const unsigned*)(bufA + ioff);
                unsigned ub = *(const unsigned*)(bufA + ioff + 128);
                h2 xa[4], xb[4];
                deq4raw(ua, xa);
                deq4raw(ub, xb);
                F8U pr_;
                #pragma unroll
                for (int k = 0; k < 4; ++k) pr_.h[k] = (xa[k] * K) * xb[k];
                acc0 = __builtin_amdgcn_mfma_f32_16x16x32_f16(
                           pr_.v, *(const f16x8*)(wbase + mf8 * 128), acc0, 0, 0, 0);
            }
            {
                int mf = mf8 + 1;
                unsigned ioff = (unsigned)(p * 256 + ((mf ^ (p & 7)) << 4) + kq * 4);
                unsigned ua = *(const unsigned*)(bufA + ioff);
                unsigned ub = *(const unsigned*)(bufA + ioff + 128);
                h2 xa[4], xb[4];
                deq4raw(ua, xa);
                deq4raw(ub, xb);
                F8U pr_;
                #pragma unroll
                for (int k = 0; k < 4; ++k) pr_.h[k] = (xa[k] * K) * xb[k];
                acc1 = __builtin_amdgcn_mfma_f32_16x16x32_f16(
                           pr_.v, *(const f16x8*)(wbase + mf * 128), acc1, 0, 0, 0);
            }
        }

        // --- stage phase 0 of NEXT batch into bufA (after bufA reads done) ---
        asm volatile("s_waitcnt lgkmcnt(0)" ::: "memory");
        __builtin_amdgcn_sched_barrier(0);
        if (more) {
            #pragma unroll
            for (int du = 0; du < 4; ++du) {
                int pr = du * 4 + q;
                const unsigned char* src = qtab + ((size_t)(unsigned)rowsN[du] << 8)
                                         + (unsigned)(((c ^ (pr & 7)) << 4));
                dma16(src, bufA + du * 1024);
            }
            asm volatile("s_waitcnt vmcnt(4)" ::: "memory");   // ph1 ready
        } else {
            asm volatile("s_waitcnt vmcnt(0)" ::: "memory");
        }

        // --- compute phase 1 from bufB (next ph0 DMAs in flight) ---
        #pragma unroll
        for (int mf8 = 0; mf8 < 8; mf8 += 2) {
            {
                int mf = 8 + mf8;
                unsigned ioff = (unsigned)(p * 256 + ((mf8 ^ (p & 7)) << 4) + kq * 4);
                unsigned ua = *(const unsigned*)(bufB + ioff);
                unsigned ub = *(const unsigned*)(bufB + ioff + 128);
                h2 xa[4], xb[4];
                deq4raw(ua, xa);
                deq4raw(ub, xb);
                F8U pr_;
                #pragma unroll
                for (int k = 0; k < 4; ++k) pr_.h[k] = (xa[k] * K) * xb[k];
                acc0 = __builtin_amdgcn_mfma_f32_16x16x32_f16(
                           pr_.v, *(const f16x8*)(wbase + mf * 128), acc0, 0, 0, 0);
            }
            {
                int mf8b = mf8 + 1;
                int mf = 8 + mf8b;
                unsigned ioff = (unsigned)(p * 256 + ((mf8b ^ (p & 7)) << 4) + kq * 4);
                unsigned ua = *(const unsigned*)(bufB + ioff);
                unsigned ub = *(const unsigned*)(bufB + ioff + 128);
                h2 xa[4], xb[4];
                deq4raw(ua, xa);
                deq4raw(ub, xb);
                F8U pr_;
                #pragma unroll
                for (int k = 0; k < 4; ++k) pr_.h[k] = (xa[k] * K) * xb[k];
                acc1 = __builtin_amdgcn_mfma_f32_16x16x32_f16(
                           pr_.v, *(const f16x8*)(wbase + mf * 128), acc1, 0, 0, 0);
            }
        }

        // --- r14/r21-verified epilogue (acc 2^-14 x rw 2^14 cancels) ---
        float v0 = (acc0[0] + acc1[0]) * rw0;
        float v1 = (acc0[1] + acc1[1]) * rw1;
        float v2 = (acc0[2] + acc1[2]) * rw2;
        float v3 = (acc0[3] + acc1[3]) * rw3;
        v0 = dpp_add<0x111>(v0); v1 = dpp_add<0x111>(v1);
        v2 = dpp_add<0x111>(v2); v3 = dpp_add<0x111>(v3);
        v0 = dpp_add<0x112>(v0); v1 = dpp_add<0x112>(v1);
        v2 = dpp_add<0x112>(v2); v3 = dpp_add<0x112>(v3);
        // lane p==3 (per kq row) holds full m-sums for pairs kq*4 + 0..3

        float d0 = 1.000001f - 0.25f * v0;
        float d1 = 1.000001f - 0.25f * v1;
        float d2 = 1.000001f - 0.25f * v2;
        float d3 = 1.000001f - 0.25f * v3;
        float a0 = pos ? d0 : fmaf(-0.5f, d0, 1.0f);
        float a1 = pos ? d1 : fmaf(-0.5f, d1, 1.0f);
        float a2 = pos ? d2 : fmaf(-0.5f, d2, 1.0f);
        float a3 = pos ? d3 : fmaf(-0.5f, d3, 1.0f);
        float lg = __logf(fmaxf(a0, 1e-8f)) + __logf(fmaxf(a1, 1e-8f)) +
                   __logf(fmaxf(a2, 1e-8f)) + __logf(fmaxf(a3, 1e-8f));
        lsum += (p == 3) ? lg : 0.f;

        #pragma unroll
        for (int du = 0; du < 4; ++du) rows[du] = rowsN[du];
    }

    // wave reduce, then block combine (one atomic)
    lsum = dpp_add<0x111>(lsum);
    lsum = dpp_add<0x112>(lsum);
    lsum = dpp_add<0x114>(lsum);
    lsum = dpp_add<0x118>(lsum);
    lsum = dpp_add<0x142>(lsum);
    lsum = dpp_add<0x143>(lsum);
    if (lane == 63) wsum[w] = lsum;
    __syncthreads();
    if (t == 0) {
        float s = wsum[0] + wsum[1] + wsum[2] + wsum[3];
        atomicAdd(out, -s);
    }
}

extern "C" void kernel_launch(void* const* d_in, const int* in_sizes, int n_in,
                              void* d_out, int out_size, void* d_ws, size_t ws_size,
                              hipStream_t stream) {
    const int*   edges  = (const int*)d_in[0];
    const int*   nedges = (const int*)d_in[1];
    const float* emb    = (const float*)d_in[2];
    const float* mh     = (const float*)d_in[3];
    float* out = (float*)d_out;

    unsigned* q4   = (unsigned*)d_ws;                             // 2 MiB fp4 table
    float*    rn_t = (float*)((char*)d_ws + (size_t)NN * DD / 2); // 128 KiB, [m][n]

    quant_norm_kernel<<<NN / 4, 256, 0, stream>>>(emb, mh, q4, rn_t, out);
    pair_kernel<<<(2 * EE) / (4 * NBW * 16), 256, 0, stream>>>(edges, nedges,
                                                               (const unsigned char*)q4,
                                                               mh, rn_t, out);
}

// Round 23
// 44.657 us; speedup vs baseline: 1.7964x; 1.0042x over previous
//
#include <hip/hip_runtime.h>
#include <math.h>

#define NN 8192
#define DD 512
#define MM 4
#define EE 131072
#define NBW 4   // 16-pair batches per wave; 1024 blocks x 4 waves x 4 x 16

typedef float  floatx2 __attribute__((ext_vector_type(2)));
typedef _Float16 h2    __attribute__((ext_vector_type(2)));
typedef _Float16 f16x8 __attribute__((ext_vector_type(8)));
typedef float  f32x4   __attribute__((ext_vector_type(4)));

union F8U { f16x8 v; h2 h[4]; uint2 u2[2]; };

__device__ inline h2 pkrtz(float a, float b) {
    return __builtin_bit_cast(h2, __builtin_amdgcn_cvt_pkrtz(a, b));
}

__device__ inline float fdot2a(h2 a, h2 b, float c) {
#if __has_builtin(__builtin_amdgcn_fdot2)
    return __builtin_amdgcn_fdot2(a, b, c, false);
#else
    return c + (float)a[0] * (float)b[0] + (float)a[1] * (float)b[1];
#endif
}

// Dequant 8 fp8 e4m3 (uint2) -> f16x8. Exact (e4m3 subset of f16). r14-verified.
__device__ inline f16x8 deq8v(uint2 u) {
    F8U o;
    floatx2 f;
    f = __builtin_amdgcn_cvt_pk_f32_fp8((int)u.x, false); o.h[0] = pkrtz(f[0], f[1]);
    f = __builtin_amdgcn_cvt_pk_f32_fp8((int)u.x, true);  o.h[1] = pkrtz(f[0], f[1]);
    f = __builtin_amdgcn_cvt_pk_f32_fp8((int)u.y, false); o.h[2] = pkrtz(f[0], f[1]);
    f = __builtin_amdgcn_cvt_pk_f32_fp8((int)u.y, true);  o.h[3] = pkrtz(f[0], f[1]);
    return o.v;
}

template <int CTRL>
__device__ inline float dpp_add(float v) {
    int x = __builtin_amdgcn_update_dpp(0, __builtin_bit_cast(int, v), CTRL, 0xf, 0xf, true);
    return v + __builtin_bit_cast(float, x);
}

__device__ inline void dma16(const void* g, void* l) {
    __builtin_amdgcn_global_load_lds(
        (const __attribute__((address_space(1))) void*)g,
        (__attribute__((address_space(3))) void*)l, 16, 0, 0);
}

// ---------------------------------------------------------------------------
// Kernel 1 (r14-verified verbatim): fp8 e4m3 row-linear table (512B/row) +
// reciprocal norms from the SAME dequantized h2 values. rn_t[m][n]. Zeroes out.
// ---------------------------------------------------------------------------
__global__ __launch_bounds__(256) void quant_norm_kernel(const float* __restrict__ emb,
                                                         const float* __restrict__ mh,
                                                         uint2* __restrict__ q,
                                                         float* __restrict__ rn_t,
                                                         float* __restrict__ out) {
    if (blockIdx.x == 0 && threadIdx.x == 0) out[0] = 0.0f;

    const int lane = threadIdx.x & 63;
    const unsigned n = blockIdx.x * 4 + (threadIdx.x >> 6);

    const float* er = emb + n * DD + lane * 8;
    float4 e0 = *(const float4*)(er);
    float4 e1 = *(const float4*)(er + 4);

    int lo = 0, hi = 0;
    lo = __builtin_amdgcn_cvt_pk_fp8_f32(e0.x, e0.y, lo, false);
    lo = __builtin_amdgcn_cvt_pk_fp8_f32(e0.z, e0.w, lo, true);
    hi = __builtin_amdgcn_cvt_pk_fp8_f32(e1.x, e1.y, hi, false);
    hi = __builtin_amdgcn_cvt_pk_fp8_f32(e1.z, e1.w, hi, true);

    uint2 u = make_uint2((unsigned)lo, (unsigned)hi);
    q[(n << 6) | lane] = u;

    F8U A; A.v = deq8v(u);
    h2 p0 = A.h[0] * A.h[0];
    h2 p1 = A.h[1] * A.h[1];
    h2 p2 = A.h[2] * A.h[2];
    h2 p3 = A.h[3] * A.h[3];

    const float* mb = mh + lane * 8;
    float ss[4];
    #pragma unroll
    for (int m = 0; m < 4; ++m) {
        float4 m0 = *(const float4*)(mb + m * DD);
        float4 m1 = *(const float4*)(mb + m * DD + 4);
        h2 w0 = pkrtz(m0.x * m0.x, m0.y * m0.y);
        h2 w1 = pkrtz(m0.z * m0.z, m0.w * m0.w);
        h2 w2 = pkrtz(m1.x * m1.x, m1.y * m1.y);
        h2 w3 = pkrtz(m1.z * m1.z, m1.w * m1.w);
        float s = 0.f;
        s = fdot2a(p0, w0, s);
        s = fdot2a(p1, w1, s);
        s = fdot2a(p2, w2, s);
        s = fdot2a(p3, w3, s);
        ss[m] = s;
    }

    ss[0] = dpp_add<0x111>(ss[0]); ss[1] = dpp_add<0x111>(ss[1]);
    ss[2] = dpp_add<0x111>(ss[2]); ss[3] = dpp_add<0x111>(ss[3]);
    ss[0] = dpp_add<0x112>(ss[0]); ss[1] = dpp_add<0x112>(ss[1]);
    ss[2] = dpp_add<0x112>(ss[2]); ss[3] = dpp_add<0x112>(ss[3]);
    ss[0] = dpp_add<0x114>(ss[0]); ss[1] = dpp_add<0x114>(ss[1]);
    ss[2] = dpp_add<0x114>(ss[2]); ss[3] = dpp_add<0x114>(ss[3]);
    ss[0] = dpp_add<0x118>(ss[0]); ss[1] = dpp_add<0x118>(ss[1]);
    ss[2] = dpp_add<0x118>(ss[2]); ss[3] = dpp_add<0x118>(ss[3]);
    ss[0] = dpp_add<0x142>(ss[0]); ss[1] = dpp_add<0x142>(ss[1]);
    ss[2] = dpp_add<0x142>(ss[2]); ss[3] = dpp_add<0x142>(ss[3]);
    ss[0] = dpp_add<0x143>(ss[0]); ss[1] = dpp_add<0x143>(ss[1]);
    ss[2] = dpp_add<0x143>(ss[2]); ss[3] = dpp_add<0x143>(ss[3]);

    if (lane == 63) {
        rn_t[0 * NN + n] = 1.0f / fmaxf(sqrtf(ss[0]), 1e-12f);
        rn_t[1 * NN + n] = 1.0f / fmaxf(sqrtf(ss[1]), 1e-12f);
        rn_t[2 * NN + n] = 1.0f / fmaxf(sqrtf(ss[2]), 1e-12f);
        rn_t[3 * NN + n] = 1.0f / fmaxf(sqrtf(ss[3]), 1e-12f);
    }
}

// ---------------------------------------------------------------------------
// Kernel 2: r22 barrier-free per-wave DMA schedule + r14 fp8 data path.
// Batch = 16 pairs; K split into 4 phases of 128B/side (4KB/phase, 4 DMAs).
// Phase ph+1's DMAs issued while computing ph; one counted vmcnt(4)/phase.
// Chunk-XOR ^pair source pre-swizzle within each 128B half (involution
// repeated on read). Dequant/weights/epilogue r14-verified.
// ---------------------------------------------------------------------------
__global__ __launch_bounds__(256) void pair_kernel(const int* __restrict__ edges,
                                                   const int* __restrict__ nedges,
                                                   const unsigned char* __restrict__ qtab,
                                                   const float* __restrict__ mh,
                                                   const float* __restrict__ rn_t,
                                                   float* __restrict__ out) {
    __shared__ __align__(16) unsigned char stage[4][8192];   // 8K/wave, 2x4KB
    __shared__ _Float16 wlds[2048];                          // 4 KiB weights
    __shared__ float wsum[4];

    const int t = threadIdx.x;
    {   // stage squared f16 weights (r14 layout: slot kk*16+kq*4+m, seq pairing)
        int m_ = t >> 6, sl = t & 63;
        const float* mb = mh + m_ * DD + sl * 8;
        float4 m0 = *(const float4*)(mb);
        float4 m1 = *(const float4*)(mb + 4);
        F8U wv;
        wv.h[0] = pkrtz(m0.x * m0.x, m0.y * m0.y);
        wv.h[1] = pkrtz(m0.z * m0.z, m0.w * m0.w);
        wv.h[2] = pkrtz(m1.x * m1.x, m1.y * m1.y);
        wv.h[3] = pkrtz(m1.z * m1.z, m1.w * m1.w);
        int s = (sl >> 2) * 16 + (sl & 3) * 4 + m_;
        *(f16x8*)(&wlds[s * 8]) = wv.v;
    }
    __syncthreads();

    const int lane = t & 63;
    const int w    = t >> 6;
    const int p    = lane & 15;   // pair / D-col
    const int kq   = lane >> 4;   // k-quad
    const int m    = p & 3;
    // DMA lane decomposition: one DMA = 4 pairs' 128B half-rows
    const int q_   = lane >> 4;         // pair-within-DMA-group
    const int side = (lane >> 3) & 1;   // 0 = row i, 1 = row j
    const int c    = lane & 7;          // 16B chunk within 128B half
    const int sEE  = side * EE;

    unsigned char* bufA = &stage[w][0];
    unsigned char* bufB = &stage[w][4096];

    const _Float16* wbase = &wlds[(kq * 4 + m) * 8];
    const float*    rm    = rn_t + m * NN;

    const int  gw   = blockIdx.x * 4 + w;     // 4096 waves x 64 pairs
    const int  base = gw * (NBW * 16);
    const bool pos  = base < EE;
    const int* eb   = pos ? edges : nedges;
    const int  lb   = pos ? base : base - EE;

    int rows[4];
    #pragma unroll
    for (int du = 0; du < 4; ++du) rows[du] = eb[lb + sEE + du * 4 + q_];

    // prologue: batch-0 phase-0 into bufA
    #pragma unroll
    for (int du = 0; du < 4; ++du) {
        int pr = du * 4 + q_;
        const unsigned char* src = qtab + ((size_t)(unsigned)rows[du] << 9)
                                 + (unsigned)((c ^ (pr & 7)) << 4);
        dma16(src, bufA + du * 1024);
    }

    float lsum = 0.f;

    #pragma unroll 1
    for (int bt = 0; bt < NBW; ++bt) {
        const int  lb2  = lb + bt * 16;
        const bool more = (bt + 1 < NBW);

        // rw + next-batch index gathers (dependent chains before new DMAs)
        int4 pi4 = *(const int4*)(eb + lb2 + kq * 4);
        int4 pj4 = *(const int4*)(eb + lb2 + EE + kq * 4);
        float rw0 = rm[pi4.x] * rm[pj4.x];
        float rw1 = rm[pi4.y] * rm[pj4.y];
        float rw2 = rm[pi4.z] * rm[pj4.z];
        float rw3 = rm[pi4.w] * rm[pj4.w];
        int rowsN[4];
        #pragma unroll
        for (int du = 0; du < 4; ++du)
            rowsN[du] = more ? eb[lb2 + 16 + sEE + du * 4 + q_] : 0;

        f32x4 acc0 = {0.f, 0.f, 0.f, 0.f};
        f32x4 acc1 = {0.f, 0.f, 0.f, 0.f};

        #pragma unroll
        for (int ph = 0; ph < 4; ++ph) {
            unsigned char* cur = (ph & 1) ? bufB : bufA;
            unsigned char* nxt = (ph & 1) ? bufA : bufB;

            // ensure prior reads of nxt are complete before overwriting it
            asm volatile("s_waitcnt lgkmcnt(0)" ::: "memory");
            __builtin_amdgcn_sched_barrier(0);

            if (ph < 3) {
                #pragma unroll
                for (int du = 0; du < 4; ++du) {
                    int pr = du * 4 + q_;
                    const unsigned char* src = qtab
                        + ((size_t)(unsigned)rows[du] << 9)
                        + (unsigned)((ph + 1) * 128)
                        + (unsigned)((c ^ (pr & 7)) << 4);
                    dma16(src, nxt + du * 1024);
                }
                asm volatile("s_waitcnt vmcnt(4)" ::: "memory");
            } else if (more) {
                #pragma unroll
                for (int du = 0; du < 4; ++du) {
                    int pr = du * 4 + q_;
                    const unsigned char* src = qtab
                        + ((size_t)(unsigned)rowsN[du] << 9)
                        + (unsigned)((c ^ (pr & 7)) << 4);
                    dma16(src, nxt + du * 1024);
                }
                asm volatile("s_waitcnt vmcnt(4)" ::: "memory");
            } else {
                asm volatile("s_waitcnt vmcnt(0)" ::: "memory");
            }

            // compute phase ph from cur: 4 MFMAs (K=128)
            #pragma unroll
            for (int ml = 0; ml < 4; ++ml) {
                int mfg = ph * 4 + ml;
                unsigned ch   = (unsigned)(ml * 2 + (kq >> 1));
                unsigned ioff = (unsigned)(p * 256) + ((ch ^ (unsigned)(p & 7)) << 4)
                              + (unsigned)((kq & 1) * 8);
                uint2 ua = *(const uint2*)(cur + ioff);
                uint2 ub = *(const uint2*)(cur + ioff + 128);
                F8U pa, pb, pr_;
                pa.v = deq8v(ua);
                pb.v = deq8v(ub);
                pr_.h[0] = pa.h[0] * pb.h[0];
                pr_.h[1] = pa.h[1] * pb.h[1];
                pr_.h[2] = pa.h[2] * pb.h[2];
                pr_.h[3] = pa.h[3] * pb.h[3];
                if (ml & 1)
                    acc1 = __builtin_amdgcn_mfma_f32_16x16x32_f16(
                               pr_.v, *(const f16x8*)(wbase + mfg * 128), acc1, 0, 0, 0);
                else
                    acc0 = __builtin_amdgcn_mfma_f32_16x16x32_f16(
                               pr_.v, *(const f16x8*)(wbase + mfg * 128), acc0, 0, 0, 0);
            }
        }

        // ---- r14-verified epilogue ----
        float v0 = (acc0[0] + acc1[0]) * rw0;
        float v1 = (acc0[1] + acc1[1]) * rw1;
        float v2 = (acc0[2] + acc1[2]) * rw2;
        float v3 = (acc0[3] + acc1[3]) * rw3;
        v0 = dpp_add<0x111>(v0); v1 = dpp_add<0x111>(v1);
        v2 = dpp_add<0x111>(v2); v3 = dpp_add<0x111>(v3);
        v0 = dpp_add<0x112>(v0); v1 = dpp_add<0x112>(v1);
        v2 = dpp_add<0x112>(v2); v3 = dpp_add<0x112>(v3);
        // lane p==3 (per kq row) holds full m-sums for pairs kq*4 + 0..3

        float d0 = 1.000001f - 0.25f * v0;
        float d1 = 1.000001f - 0.25f * v1;
        float d2 = 1.000001f - 0.25f * v2;
        float d3 = 1.000001f - 0.25f * v3;
        float a0 = pos ? d0 : fmaf(-0.5f, d0, 1.0f);
        float a1 = pos ? d1 : fmaf(-0.5f, d1, 1.0f);
        float a2 = pos ? d2 : fmaf(-0.5f, d2, 1.0f);
        float a3 = pos ? d3 : fmaf(-0.5f, d3, 1.0f);
        float lg = __logf(fmaxf(a0, 1e-8f)) + __logf(fmaxf(a1, 1e-8f)) +
                   __logf(fmaxf(a2, 1e-8f)) + __logf(fmaxf(a3, 1e-8f));
        lsum += (p == 3) ? lg : 0.f;

        #pragma unroll
        for (int du = 0; du < 4; ++du) rows[du] = rowsN[du];
    }

    // wave reduce, then block combine (one atomic)
    lsum = dpp_add<0x111>(lsum);
    lsum = dpp_add<0x112>(lsum);
    lsum = dpp_add<0x114>(lsum);
    lsum = dpp_add<0x118>(lsum);
    lsum = dpp_add<0x142>(lsum);
    lsum = dpp_add<0x143>(lsum);
    if (lane == 63) wsum[w] = lsum;
    __syncthreads();
    if (t == 0) {
        float s = wsum[0] + wsum[1] + wsum[2] + wsum[3];
        atomicAdd(out, -s);
    }
}

extern "C" void kernel_launch(void* const* d_in, const int* in_sizes, int n_in,
                              void* d_out, int out_size, void* d_ws, size_t ws_size,
                              hipStream_t stream) {
    const int*   edges  = (const int*)d_in[0];
    const int*   nedges = (const int*)d_in[1];
    const float* emb    = (const float*)d_in[2];
    const float* mh     = (const float*)d_in[3];
    float* out = (float*)d_out;

    uint2* q    = (uint2*)d_ws;                                  // 4 MiB fp8 table
    float* rn_t = (float*)((char*)d_ws + (size_t)NN * DD);       // 128 KiB, [m][n]

    quant_norm_kernel<<<NN / 4, 256, 0, stream>>>(emb, mh, q, rn_t, out);
    pair_kernel<<<(2 * EE) / (4 * NBW * 16), 256, 0, stream>>>(edges, nedges,
                                                               (const unsigned char*)q,
                                                               mh, rn_t, out);
}